// Round 14
// baseline (464.827 us; speedup 1.0000x reference)
//
#include <hip/hip_runtime.h>
#include <hip/hip_bf16.h>

// GGCN: g1=relu(A@(x@W1)+b1); g2=relu(A@(g1@W2)+b2); out=relu(g2@Wd1+bd1)@Wd2+bd2
// N=16384, F=32, H=64, A dense f32 (1.07 GB, read 2x -> HBM floor ~341us).
// R14 = R12's A-path (256B granule, plain loads - both proven) + BM=128 via
// grid 512 = 128 rowblks x 4 kq (kq=bid&3 constant per XCD -> 512KB hot Ht
// slice per XCD L2). Halves logical Ht reads (512->256 MB/dispatch) - the
// mechanism that bought 55us in R5->R6. 4 waves x 32 rows, shared H tile
// (8KB dbuf) staged cooperatively w/ R1's 2-barrier loop (proven neutral).
// LDS 48KB -> 2 blocks/CU (2x R12 occupancy). Partials gP[4] + R4 reduce.

typedef __bf16 bf16x8 __attribute__((ext_vector_type(8)));
typedef float  f32x16 __attribute__((ext_vector_type(16)));
typedef float  f32x4v __attribute__((ext_vector_type(4)));
typedef int    i32x4  __attribute__((ext_vector_type(4)));

#define NNODE 16384
#define KDIM  16384
#define HCOL  64

__device__ inline i32x4 pack8(f32x4v a, f32x4v b){
  bf16x8 t;
  t[0]=(__bf16)a[0]; t[1]=(__bf16)a[1]; t[2]=(__bf16)a[2]; t[3]=(__bf16)a[3];
  t[4]=(__bf16)b[0]; t[5]=(__bf16)b[1]; t[6]=(__bf16)b[2]; t[7]=(__bf16)b[3];
  return __builtin_bit_cast(i32x4, t);
}
#define BC(x) __builtin_bit_cast(bf16x8, x)

// ---------------- big kernel: gP[kq] = A[rows, kq-quarter] @ Ht^T ----------------
// block = 256 thr (4 waves x 32-row groups). BM=128. Tile = {32r A, 64r H} x 64k.
// LDS: sA (wid,buf) 32x8 chunks = 32 KB ; sH (buf) 64x8 chunks = 16 KB.
__global__ __launch_bounds__(256, 2) void gcn_layer_kernel(
    const float* __restrict__ A,      // [16384][16384] f32
    const __bf16* __restrict__ Ht,    // [64][16384] bf16 (transposed H)
    float* __restrict__ gP)           // [4][16384][64] f32 partials
{
  __shared__ i32x4 sA[4*2*256];   // (wid,buf) x 32 rows x 8 chunks
  __shared__ i32x4 sH[2*512];     // (buf) x 64 rows x 8 chunks

  const int tid  = threadIdx.x;
  const int lane = tid & 63;
  const int wid  = tid >> 6;          // 32-row group 0..3
  const int bid  = blockIdx.x;
  const int kq   = bid & 3;           // K-quarter: constant per XCD (bid%8 rr map)
  const int row0 = (bid >> 2) * 128 + wid * 32;

  const int rA0  = lane >> 3;         // 0..7 staging row-in-group
  const int ccA  = lane & 7;          // staging logical 16B chunk (8 per 64k row)
  const int swzA = ccA ^ rA0;         // XOR swizzle (row&7 == rA0)
  const int r    = lane & 31;
  const int hsub = lane >> 5;         // 8-k half of the 16-k MFMA window
  const int xs   = r & 7;

  // H cooperative staging: thread -> h-row tid>>2, chunk pair (32B contiguous)
  const int hrow = tid >> 2;
  const int cc2  = (tid & 3) * 2;

  const size_t k0 = (size_t)kq * 4096;

  f32x4v ra[8]; i32x4 rh[2];

  const float* pA0 = A + (size_t)(row0 + rA0) * KDIM + k0 + (size_t)ccA*8;
  const i32x4* pH0 = (const i32x4*)(Ht + (size_t)hrow * KDIM + k0) + cc2;

  auto stage_load = [&](int t){
    const float* pA = pA0 + (size_t)t*64;
    #pragma unroll
    for (int pi=0; pi<4; ++pi){                    // rows rA0 + pi*8 (32 rows)
      const float* p = pA + (size_t)pi*8*KDIM;
      ra[2*pi]   = *(const f32x4v*)p;              // plain loads [R12-proven]
      ra[2*pi+1] = *(const f32x4v*)(p+4);
    }
    rh[0] = pH0[(size_t)t*8];                      // Ht: L2-resident 512KB slice
    rh[1] = pH0[(size_t)t*8 + 1];
  };

  auto stage_write = [&](int buf){
    i32x4* dA = &sA[(wid*2+buf)*256];
    #pragma unroll
    for (int pi=0; pi<4; ++pi)
      dA[(rA0 + pi*8)*8 + swzA] = pack8(ra[2*pi], ra[2*pi+1]);
    i32x4* dH = &sH[buf*512 + hrow*8];
    dH[cc2 ^ (hrow & 7)]     = rh[0];
    dH[(cc2+1) ^ (hrow & 7)] = rh[1];
  };

  f32x16 acc0 = {}, acc1 = {};

  auto compute = [&](int buf){
    const i32x4* bA = &sA[(wid*2+buf)*256];
    const i32x4* bH = &sH[buf*512];
    #pragma unroll
    for (int kk=0; kk<4; ++kk){
      int c = (kk*2 + hsub) ^ xs;
      bf16x8 a0 = BC(bA[r*8 + c]);
      bf16x8 b0 = BC(bH[r*8 + c]);
      bf16x8 b1 = BC(bH[(r+32)*8 + c]);
      acc0 = __builtin_amdgcn_mfma_f32_32x32x16_bf16(a0, b0, acc0, 0,0,0);
      acc1 = __builtin_amdgcn_mfma_f32_32x32x16_bf16(a0, b1, acc1, 0,0,0);
    }
  };

  // R1-style 2-barrier dbuf pipeline over 64 tiles (k-quarter, 64 k each)
  stage_load(0);
  stage_write(0);
  stage_load(1);
  __syncthreads();
  #pragma unroll 1
  for (int t=0; t<63; ++t){
    int nx = t+2; if (nx > 63) nx = 63;   // tail: redundant re-load, cache-hit
    compute(t&1);
    __syncthreads();
    stage_write((t+1)&1);
    stage_load(nx);
    __syncthreads();
  }
  compute(1);                  // tile 63

  // epilogue: store this wave's 32x64 partial (wave-private rows, no sync)
  float* out = gP + ((size_t)kq * NNODE + row0) * HCOL;
  #pragma unroll
  for (int j=0; j<16; ++j){
    int rr = (j&3) + 8*(j>>2) + 4*hsub;   // C/D layout [verified R1..R13]
    out[(size_t)rr * HCOL + r]      = acc0[j];
    out[(size_t)rr * HCOL + 32 + r] = acc1[j];
  }
}

// ---------------- reduce: g = relu(sum_4 partials + bias) ----------------
__global__ __launch_bounds__(256) void reduce_kernel(
    const float* __restrict__ gP,    // [4][16384][64]
    const float* __restrict__ bias,  // [64]
    float* __restrict__ g)           // [16384][64]
{
  const size_t i = (size_t)blockIdx.x * 256 + threadIdx.x;   // f32x4 index
  const f32x4v* p = (const f32x4v*)gP;
  f32x4v s = p[i];
  s += p[i +  262144];
  s += p[i +  524288];
  s += p[i +  786432];
  f32x4v b = *(const f32x4v*)(bias + (i & 15) * 4);
  f32x4v o;
  o[0] = fmaxf(s[0] + b[0], 0.f);
  o[1] = fmaxf(s[1] + b[1], 0.f);
  o[2] = fmaxf(s[2] + b[2], 0.f);
  o[3] = fmaxf(s[3] + b[3], 0.f);
  ((f32x4v*)g)[i] = o;
}

// ---------------- projection: out[h][n] = sum_f in[n][f]*W[f][h], bf16 out ----------------
template<int F>
__global__ __launch_bounds__(128) void proj_T_kernel(
    const float* __restrict__ in,   // [N][F]
    const float* __restrict__ W,    // [F][64]
    __bf16* __restrict__ out)       // [64][N]
{
  constexpr int FP = F + 4;
  __shared__ float sWt[64*FP];
  __shared__ short sOut[64*136];

  int tid = threadIdx.x;
  for (int e = tid; e < 64*F; e += 128){
    int h = e / F, j = e - h*F;
    sWt[h*FP + j] = W[j*64 + h];
  }
  __syncthreads();

  const size_t n = (size_t)blockIdx.x*128 + tid;
  float rowv[F];
  #pragma unroll
  for (int j=0; j<F; j+=4){
    f32x4v v = *(const f32x4v*)(in + n*F + j);
    rowv[j]=v[0]; rowv[j+1]=v[1]; rowv[j+2]=v[2]; rowv[j+3]=v[3];
  }
  #pragma unroll
  for (int h=0; h<64; ++h){
    float s = 0.f;
    #pragma unroll
    for (int j=0; j<F; j+=4){
      f32x4v w = *(const f32x4v*)&sWt[h*FP + j];
      s += rowv[j]*w[0] + rowv[j+1]*w[1] + rowv[j+2]*w[2] + rowv[j+3]*w[3];
    }
    sOut[h*136 + tid] = __builtin_bit_cast(short, (__bf16)s);
  }
  __syncthreads();

  const size_t n0 = (size_t)blockIdx.x*128;
  #pragma unroll
  for (int pi=0; pi<8; ++pi){
    int p = pi*128 + tid;
    int h = p >> 4, cc = p & 15;
    i32x4 v = *(const i32x4*)&sOut[h*136 + cc*8];
    *(i32x4*)(out + (size_t)h*NNODE + n0 + cc*8) = v;
  }
}

// ---------------- tail MLP: out[n] = relu(g2[n]@Wd1+bd1)@Wd2 + bd2 ----------------
__global__ __launch_bounds__(256) void tail_kernel(
    const float* __restrict__ g2,
    const float* __restrict__ Wd1,
    const float* __restrict__ bd1,
    const float* __restrict__ Wd2,
    const float* __restrict__ bd2,
    float* __restrict__ outp)
{
  __shared__ float sW[64*32];
  __shared__ float sb1[32], sw2[32];
  int tid = threadIdx.x;
  for (int e=tid; e<2048; e+=256) sW[e] = Wd1[e];
  if (tid < 32){ sb1[tid] = bd1[tid]; sw2[tid] = Wd2[tid]; }
  __syncthreads();

  size_t n = (size_t)blockIdx.x*256 + tid;
  float rv[64];
  #pragma unroll
  for (int j=0;j<64;j+=4){
    f32x4v v = *(const f32x4v*)(g2 + n*64 + j);
    rv[j]=v[0]; rv[j+1]=v[1]; rv[j+2]=v[2]; rv[j+3]=v[3];
  }
  float o = 0.f;
  #pragma unroll
  for (int c=0;c<32;++c){
    float s = sb1[c];
    #pragma unroll
    for (int j=0;j<64;++j) s += rv[j]*sW[j*32 + c];
    o += fmaxf(s, 0.f) * sw2[c];
  }
  outp[n] = o + bd2[0];
}

extern "C" void kernel_launch(void* const* d_in, const int* in_sizes, int n_in,
                              void* d_out, int out_size, void* d_ws, size_t ws_size,
                              hipStream_t stream)
{
  const float* x   = (const float*)d_in[0];
  const float* a   = (const float*)d_in[1];
  const float* W1  = (const float*)d_in[2];
  const float* b1  = (const float*)d_in[3];
  const float* W2  = (const float*)d_in[4];
  const float* b2  = (const float*)d_in[5];
  const float* Wd1 = (const float*)d_in[6];
  const float* bd1 = (const float*)d_in[7];
  const float* Wd2 = (const float*)d_in[8];
  const float* bd2 = (const float*)d_in[9];
  float* outp = (float*)d_out;

  char* ws = (char*)d_ws;                       // needs 28 MB
  __bf16* Ht1 = (__bf16*)(ws);                  // [64][16384] bf16, 2 MB
  __bf16* Ht2 = (__bf16*)(ws + (2u<<20));       // 2 MB
  float*  g1  = (float*)(ws + (4u<<20));        // [16384][64] f32, 4 MB
  float*  g2  = (float*)(ws + (8u<<20));        // 4 MB
  float*  gP  = (float*)(ws + (12u<<20));       // [4][16384][64] f32, 16 MB

  proj_T_kernel<32><<<128, 128, 0, stream>>>(x,  W1, Ht1);
  gcn_layer_kernel <<<512, 256, 0, stream>>>(a, Ht1, gP);
  reduce_kernel    <<<1024, 256, 0, stream>>>(gP, b1, g1);
  proj_T_kernel<64><<<128, 128, 0, stream>>>(g1, W2, Ht2);
  gcn_layer_kernel <<<512, 256, 0, stream>>>(a, Ht2, gP);
  reduce_kernel    <<<1024, 256, 0, stream>>>(gP, b2, g2);
  tail_kernel      <<<64, 256, 0, stream>>>(g2, Wd1, bd1, Wd2, bd2, outp);
}